// Round 4
// baseline (560.472 us; speedup 1.0000x reference)
//
#include <hip/hip_runtime.h>
#include <hip/hip_bf16.h>
#include <cstdint>

// HungarianMatcher cost via MFMA, round 4.
// R1: LDS-atomic histogram = DS-pipe-bound (815us).
// R2: on-the-fly one-hot B build = 43% of VALU issue (240us).
// R3: precomputed B fragments; VALUBusy 47->31% but dur 240->227: kernel is
//     latency-bound — grid 770 blocks = only 12 waves/CU (Occupancy 16%),
//     all pipes <35%. Fix: KC 110->200 (4+ blocks/CU), single-buffer B
//     (L2-resident, ~200cy covered by point_math), prefetch only pred (HBM).

#define FOCAL_ALPHA 0.25f
constexpr int NMAX   = 128;
constexpr int NTILES = 7;      // 7 x 16 = 112 cols >= N=100
constexpr int BLOCK  = 256;    // 4 waves, each owns one 16-row q-strip
constexpr int KC     = 200;    // K-chunks: 200*7=1400 blocks ~ 4-5 blocks/CU

typedef __attribute__((ext_vector_type(8))) short short8;
typedef __attribute__((ext_vector_type(4))) float f32x4;

// 17 VALU ops (3 quarter-rate trans). Safe for |x| < 80 (inputs ~N(0,1)).
__device__ __forceinline__ void point_math(float x, float& d, float& f0o, float& po) {
    float e  = __expf(-x);                      // e^{-x}
    float a  = 1.0f + e;
    float p  = __builtin_amdgcn_rcpf(a);        // sigmoid(x)
    float l  = __logf(a);                       // -log sigmoid(x)
    float lm = -x - l;                          // log(1 - sigmoid(x))
    float om = e * p;                           // 1 - p
    float f1 = FOCAL_ALPHA * (om * om) * l;
    float f0 = -(1.0f - FOCAL_ALPHA) * (p * p) * lm;
    d   = f1 - f0;
    f0o = f0;
    po  = p;
}

__device__ __forceinline__ uint32_t pack_bf16_trunc(float lo, float hi) {
    return __builtin_amdgcn_perm(__float_as_uint(hi), __float_as_uint(lo), 0x07060302u);
}

// Bpre[step][tile][lane] = uint4 = 8 bf16 one-hot B-fragment values.
__global__ __launch_bounds__(256) void
build_B(const int* __restrict__ labels, uint4* __restrict__ Bpre, int steps) {
    int tid  = blockIdx.x * 256 + threadIdx.x;
    int step = tid >> 6;
    int lane = tid & 63;
    if (step >= steps) return;
    const int quad = lane >> 4;
    const int m    = lane & 15;
    const int base = step * 32 + quad * 8;
    int4 l0 = *(const int4*)(labels + base);
    int4 l1 = *(const int4*)(labels + base + 4);
    int ls[8] = {l0.x, l0.y, l0.z, l0.w, l1.x, l1.y, l1.z, l1.w};
    #pragma unroll
    for (int t = 0; t < NTILES; ++t) {
        const int tgt = t * 16 + m;
        uint32_t u[4];
        #pragma unroll
        for (int i = 0; i < 4; ++i) {
            uint32_t lo = (ls[2*i]   == tgt) ? 0x00003F80u : 0u;
            uint32_t hi = (ls[2*i+1] == tgt) ? 0x3F800000u : 0u;
            u[i] = lo | hi;
        }
        Bpre[((size_t)step * NTILES + t) * 64 + lane] = make_uint4(u[0], u[1], u[2], u[3]);
    }
}

union BU { uint4 q; short8 v; uint32_t u[4]; };

__global__ __launch_bounds__(BLOCK, 4) void
matcher_main_pre(const float* __restrict__ pred, const uint4* __restrict__ Bpre,
                 float* __restrict__ S1, float* __restrict__ S2,
                 float* __restrict__ sumf0, float* __restrict__ sump,
                 int Q, int P, int N) {
    const int tid  = threadIdx.x;
    const int wave = tid >> 6;
    const int lane = tid & 63;
    const int m    = lane & 15;
    const int quad = lane >> 4;

    const int strip = blockIdx.y * 4 + wave;
    const int q0    = strip * 16;
    if (q0 >= Q) return;               // no barriers: safe

    const int total_steps = P >> 5;
    const int per         = (total_steps + KC - 1) / KC;
    const int s0          = blockIdx.x * per;
    const int s1          = min(s0 + per, total_steps);
    if (s0 >= s1) return;

    const float* prb = pred + (size_t)(q0 + m) * P + quad * 8;
    const uint4* bpb = Bpre + lane;

    f32x4 c1[NTILES], c2[NTILES];
    #pragma unroll
    for (int t = 0; t < NTILES; ++t) {
        c1[t] = (f32x4){0.f, 0.f, 0.f, 0.f};
        c2[t] = (f32x4){0.f, 0.f, 0.f, 0.f};
    }
    float sf0 = 0.0f, sp = 0.0f;

    // preload A for first step (HBM latency — prefetched one step ahead)
    {
        const float* pa = prb + (size_t)s0 * 32;
        // fallthrough into loop with ax regs
    }
    float4 ax0 = *(const float4*)(prb + (size_t)s0 * 32);
    float4 ax1 = *(const float4*)(prb + (size_t)s0 * 32 + 4);

    for (int s = s0; s < s1; ++s) {
        // B for this step: L2/L3-resident, latency covered by point_math below
        const uint4* bp = bpb + (size_t)s * (NTILES * 64);
        BU b[NTILES];
        #pragma unroll
        for (int t = 0; t < NTILES; ++t) b[t].q = bp[t * 64];

        // prefetch next step's A (clamped: last iter reloads current, unused)
        const int sn = (s + 1 < s1) ? s + 1 : s;
        const float* pn = prb + (size_t)sn * 32;
        float4 nx0 = *(const float4*)pn;
        float4 nx1 = *(const float4*)(pn + 4);

        float xs[8] = {ax0.x, ax0.y, ax0.z, ax0.w, ax1.x, ax1.y, ax1.z, ax1.w};
        float v[8], pv[8];
        #pragma unroll
        for (int j = 0; j < 8; ++j) {
            float f0j;
            point_math(xs[j], v[j], f0j, pv[j]);
            sf0 += f0j;
            sp  += pv[j];
        }

        BU A1, A2;
        #pragma unroll
        for (int i = 0; i < 4; ++i) {
            A1.u[i] = pack_bf16_trunc(v[2*i],  v[2*i+1]);
            A2.u[i] = pack_bf16_trunc(pv[2*i], pv[2*i+1]);
        }

        #pragma unroll
        for (int t = 0; t < NTILES; ++t) {
            c1[t] = __builtin_amdgcn_mfma_f32_16x16x32_bf16(A1.v, b[t].v, c1[t], 0, 0, 0);
            c2[t] = __builtin_amdgcn_mfma_f32_16x16x32_bf16(A2.v, b[t].v, c2[t], 0, 0, 0);
        }

        ax0 = nx0; ax1 = nx1;
    }

    sf0 += __shfl_xor(sf0, 16, 64);
    sf0 += __shfl_xor(sf0, 32, 64);
    sp  += __shfl_xor(sp, 16, 64);
    sp  += __shfl_xor(sp, 32, 64);
    if (lane < 16) {
        unsafeAtomicAdd(&sumf0[q0 + lane], sf0);
        unsafeAtomicAdd(&sump[q0 + lane], sp);
    }

    // C/D layout: col = lane&15 (+16t), row = quad*4 + reg
    #pragma unroll
    for (int t = 0; t < NTILES; ++t) {
        const int col = t * 16 + m;
        if (col < N) {
            #pragma unroll
            for (int r = 0; r < 4; ++r) {
                const int row = q0 + quad * 4 + r;
                unsafeAtomicAdd(&S1[(size_t)row * N + col], c1[t][r]);
                unsafeAtomicAdd(&S2[(size_t)row * N + col], c2[t][r]);
            }
        }
    }
}

// Fallback (ws too small for Bpre): on-the-fly B build.
__global__ __launch_bounds__(BLOCK) void
matcher_main_fly(const float* __restrict__ pred, const int* __restrict__ labels,
                 float* __restrict__ S1, float* __restrict__ S2,
                 float* __restrict__ sumf0, float* __restrict__ sump,
                 int Q, int P, int N) {
    const int tid  = threadIdx.x;
    const int wave = tid >> 6;
    const int lane = tid & 63;
    const int m    = lane & 15;
    const int quad = lane >> 4;

    const int strip = blockIdx.y * 4 + wave;
    const int q0    = strip * 16;
    if (q0 >= Q) return;

    const int total_steps = P >> 5;
    const int per         = (total_steps + KC - 1) / KC;
    const int s0          = blockIdx.x * per;
    const int s1          = min(s0 + per, total_steps);
    if (s0 >= s1) return;

    const float* prb = pred + (size_t)(q0 + m) * P + quad * 8;
    const int*   lrb = labels + quad * 8;

    f32x4 c1[NTILES], c2[NTILES];
    #pragma unroll
    for (int t = 0; t < NTILES; ++t) {
        c1[t] = (f32x4){0.f, 0.f, 0.f, 0.f};
        c2[t] = (f32x4){0.f, 0.f, 0.f, 0.f};
    }
    float sf0 = 0.0f, sp = 0.0f;

    for (int s = s0; s < s1; ++s) {
        const float* pa = prb + (size_t)s * 32;
        const int*   la = lrb + (size_t)s * 32;
        float4 x0 = *(const float4*)pa;
        float4 x1 = *(const float4*)(pa + 4);
        int4   l0 = *(const int4*)la;
        int4   l1 = *(const int4*)(la + 4);

        float xs[8] = {x0.x, x0.y, x0.z, x0.w, x1.x, x1.y, x1.z, x1.w};
        int   ls[8] = {l0.x, l0.y, l0.z, l0.w, l1.x, l1.y, l1.z, l1.w};
        float v[8], pv[8];
        #pragma unroll
        for (int j = 0; j < 8; ++j) {
            float f0j;
            point_math(xs[j], v[j], f0j, pv[j]);
            sf0 += f0j;
            sp  += pv[j];
        }

        BU A1, A2;
        #pragma unroll
        for (int i = 0; i < 4; ++i) {
            A1.u[i] = pack_bf16_trunc(v[2*i],  v[2*i+1]);
            A2.u[i] = pack_bf16_trunc(pv[2*i], pv[2*i+1]);
        }

        #pragma unroll
        for (int t = 0; t < NTILES; ++t) {
            const int tgt = t * 16 + m;
            BU B;
            #pragma unroll
            for (int i = 0; i < 4; ++i) {
                uint32_t lo = (ls[2*i]   == tgt) ? 0x00003F80u : 0u;
                uint32_t hi = (ls[2*i+1] == tgt) ? 0x3F800000u : 0u;
                B.u[i] = lo | hi;
            }
            c1[t] = __builtin_amdgcn_mfma_f32_16x16x32_bf16(A1.v, B.v, c1[t], 0, 0, 0);
            c2[t] = __builtin_amdgcn_mfma_f32_16x16x32_bf16(A2.v, B.v, c2[t], 0, 0, 0);
        }
    }

    sf0 += __shfl_xor(sf0, 16, 64);
    sf0 += __shfl_xor(sf0, 32, 64);
    sp  += __shfl_xor(sp, 16, 64);
    sp  += __shfl_xor(sp, 32, 64);
    if (lane < 16) {
        unsafeAtomicAdd(&sumf0[q0 + lane], sf0);
        unsafeAtomicAdd(&sump[q0 + lane], sp);
    }

    #pragma unroll
    for (int t = 0; t < NTILES; ++t) {
        const int col = t * 16 + m;
        if (col < N) {
            #pragma unroll
            for (int r = 0; r < 4; ++r) {
                const int row = q0 + quad * 4 + r;
                unsafeAtomicAdd(&S1[(size_t)row * N + col], c1[t][r]);
                unsafeAtomicAdd(&S2[(size_t)row * N + col], c2[t][r]);
            }
        }
    }
}

__global__ __launch_bounds__(256) void
matcher_counts(const int* __restrict__ labels, int* __restrict__ counts, int P, int N) {
    __shared__ int c[NMAX];
    for (int i = threadIdx.x; i < NMAX; i += 256) c[i] = 0;
    __syncthreads();
    const int stride = gridDim.x * 256;
    for (int i = blockIdx.x * 256 + threadIdx.x; i < P; i += stride)
        atomicAdd(&c[labels[i]], 1);
    __syncthreads();
    for (int j = threadIdx.x; j < N; j += 256)
        if (c[j] != 0) atomicAdd(&counts[j], c[j]);
}

__global__ __launch_bounds__(256) void
matcher_final(const float* __restrict__ S1, const float* __restrict__ S2,
              const float* __restrict__ sumf0, const float* __restrict__ sump,
              const int* __restrict__ counts, float* __restrict__ out,
              int Q, int P, int N) {
    int idx = blockIdx.x * 256 + threadIdx.x;
    if (idx >= Q * N) return;
    int q = idx / N;
    int j = idx - q * N;
    float invP = 1.0f / (float)P;
    float cost_mask = (S1[idx] + sumf0[q]) * invP;
    float cost_dice = 1.0f - (2.0f * S2[idx] + 1.0f) / (sump[q] + (float)counts[j] + 1.0f);
    out[idx] = cost_mask + cost_dice;
}

extern "C" void kernel_launch(void* const* d_in, const int* in_sizes, int n_in,
                              void* d_out, int out_size, void* d_ws, size_t ws_size,
                              hipStream_t stream) {
    const float* pred   = (const float*)d_in[0];
    const int*   labels = (const int*)d_in[1];
    const int P = in_sizes[1];
    const int Q = in_sizes[0] / P;
    const int N = out_size / Q;

    float* S1     = (float*)d_ws;
    float* S2     = S1 + (size_t)Q * N;
    float* sumf0  = S2 + (size_t)Q * N;
    float* sump   = sumf0 + Q;
    int*   counts = (int*)(sump + Q);
    size_t base_bytes = ((size_t)2 * Q * N + 2 * Q + N) * sizeof(float);

    const int steps = P >> 5;
    size_t bpre_off   = (base_bytes + 255) & ~(size_t)255;
    size_t bpre_bytes = (size_t)steps * NTILES * 64 * sizeof(uint4);
    bool use_pre = (ws_size >= bpre_off + bpre_bytes);

    hipMemsetAsync(d_ws, 0, base_bytes, stream);
    matcher_counts<<<128, 256, 0, stream>>>(labels, counts, P, N);

    const int strips = (Q + 15) / 16;
    dim3 grid(KC, (strips + 3) / 4);

    if (use_pre) {
        uint4* Bpre = (uint4*)((char*)d_ws + bpre_off);
        build_B<<<(steps * 64 + 255) / 256, 256, 0, stream>>>(labels, Bpre, steps);
        matcher_main_pre<<<grid, BLOCK, 0, stream>>>(pred, Bpre, S1, S2, sumf0, sump, Q, P, N);
    } else {
        matcher_main_fly<<<grid, BLOCK, 0, stream>>>(pred, labels, S1, S2, sumf0, sump, Q, P, N);
    }

    int qn = Q * N;
    matcher_final<<<(qn + 255) / 256, 256, 0, stream>>>(S1, S2, sumf0, sump, counts,
                                                        (float*)d_out, Q, P, N);
}